// Round 3
// baseline (24433.450 us; speedup 1.0000x reference)
//
#include <hip/hip_runtime.h>
#include <cstdint>
#include <cstddef>

// Problem constants
#define W_IMG 128
#define HW    16384            // 128*128
#define T_STEPS 20
#define BATCH 8
#define Y_SIZE 2621440         // 20*8*16384
#define HS_SLICE 1048576       // 8*8*16384  (one [t,s] slice)

__device__ __forceinline__ float sigm(float x) { return 1.0f / (1.0f + __expf(-x)); }
// tanh(x) = 1 - 2/(exp(2x)+1); safe at +/-inf, no NaN
__device__ __forceinline__ float tanh_fast(float x) { return 1.0f - 2.0f / (__expf(2.0f * x) + 1.0f); }

// ---------------------------------------------------------------------------
// Weight transpose: orig [oc][ic][3][3]  ->  wT [ic][ky][kx][oc(8)]
// wT lives in the hs[19,3] slice of d_out (written before use, zeroed last).
// ---------------------------------------------------------------------------
struct PrepArgs {
    const float* w[12];
    float* wT;
};

__global__ __launch_bounds__(256) void prep_kernel(PrepArgs a) {
    const int IC[12]  = {9, 9, 9, 16, 16, 16, 16, 16, 16, 8, 8, 8};
    const int OCc[12] = {8, 8, 8, 8, 8, 8, 8, 8, 8, 8, 8, 1};
    const int OFF[12] = {0, 648, 1296, 1944, 3096, 4248, 5400, 6552, 7704, 8856, 9432, 10008};
    const int c = blockIdx.x;           // one conv per block (grid = 12)
    const int n = IC[c] * 72;           // ic*9 taps * 8 oc (oc padded to 8)
    const float* ws = a.w[c];
    float* wd = a.wT + OFF[c];
    for (int i = threadIdx.x; i < n; i += 256) {
        const int o = i & 7;
        const int rest = i >> 3;                 // ic*9 + tap
        const int ic = rest / 9, tap = rest - ic * 9;
        float v = 0.0f;
        if (o < OCc[c]) v = ws[(o * IC[c] + ic) * 9 + tap];
        wd[i] = v;                               // dest index == (ic*9+tap)*8 + o == i
    }
}

// ---------------------------------------------------------------------------
// Fused GRU cell: one 16(y)x32(x) output tile, 512 threads (1 center px each).
// Per input channel (staged once in LDS, zero-padded):
//   - z-conv + h-conv-x-part accumulate at the center px
//   - r-conv accumulates on the extended halo (16+2D)x(32+2D) (KP=2 px/thr)
// Then rh = sigmoid(r + br) * hprev is built IN LDS on the halo region
// (hprev zero-padded => rh==0 outside image, matching the reference's
// zero-padded conv input), and the h-conv rh-part runs immediately.
// This removes the separate h kernel, the z/rh global round-trip, and the
// second staging pass of the same inputs. z never leaves registers.
// ---------------------------------------------------------------------------
template <int D, int XN>
__device__ void fused_unit(const float* __restrict__ xb, const float* __restrict__ hprev,
                           float* __restrict__ outp,
                           const float* __restrict__ wTz, const float* __restrict__ wTr,
                           const float* __restrict__ wTh,
                           const float* __restrict__ bz, const float* __restrict__ br,
                           const float* __restrict__ bh,
                           int y0, int x0, float* __restrict__ stage, float* __restrict__ rhb) {
    constexpr int Ey = 16 + 2 * D, Ex = 32 + 2 * D, NE = Ey * Ex;   // rh halo region
    constexpr int SRx = 32 + 4 * D, SRt = (16 + 4 * D) * SRx;       // staged region
    constexpr int NS = (SRt + 511) / 512;                           // stage slots/thread
    const int tid = threadIdx.x;
    const int ry = tid >> 5, rx = tid & 31;
    const int gy = y0 + ry, gx = x0 + rx;

    // Per-thread staging slots (hoisted out of the ic loop)
    int sgoff[NS]; bool sinb[NS], swr[NS];
#pragma unroll
    for (int s = 0; s < NS; s++) {
        const int i = s * 512 + tid;
        const int sy = i / SRx, sx = i - sy * SRx;
        const int yy = y0 - 2 * D + sy, xx = x0 - 2 * D + sx;
        swr[s] = (i < SRt);
        sinb[s] = swr[s] && ((unsigned)yy < 128u) && ((unsigned)xx < 128u);
        sgoff[s] = sinb[s] ? (yy * W_IMG + xx) : 0;
    }

    // Per-thread halo px assignment (2 slots; slot0 always active since NE>512)
    int hbase1, hgoff0, hgoff1; bool hact1, hinb0, hinb1;
    {
        const int ey = tid / Ex, ex = tid - ey * Ex;
        const int yy = y0 - D + ey, xx = x0 - D + ex;
        hinb0 = ((unsigned)yy < 128u) && ((unsigned)xx < 128u);
        hgoff0 = hinb0 ? (yy * W_IMG + xx) : 0;
    }
    const int hbase0 = (tid / Ex) * SRx + (tid - (tid / Ex) * Ex);
    {
        const int p = 512 + tid;
        const int ey = p / Ex, ex = p - ey * Ex;
        const int yy = y0 - D + ey, xx = x0 - D + ex;
        hact1 = (p < NE);
        hinb1 = hact1 && ((unsigned)yy < 128u) && ((unsigned)xx < 128u);
        hbase1 = ey * SRx + ex;
        hgoff1 = hinb1 ? (yy * W_IMG + xx) : 0;
    }
    const int cbase = (ry + D) * SRx + (rx + D);
    const bool has_h = (hprev != nullptr);

    float az[8], ah[8], ar0[8], ar1[8];
#pragma unroll
    for (int o = 0; o < 8; o++) { az[o] = 0.0f; ah[o] = 0.0f; ar0[o] = 0.0f; ar1[o] = 0.0f; }

    auto stage_ch = [&](const float* src) {
        __syncthreads();               // previous channel's LDS reads done
#pragma unroll
        for (int s = 0; s < NS; s++) {
            float v = 0.0f;
            if (sinb[s]) v = src[sgoff[s]];
            if (swr[s]) stage[s * 512 + tid] = v;
        }
        __syncthreads();
    };

    // x channels: z-conv (center) + h-conv x-part (center) + r-conv (halo)
    for (int ic = 0; ic < XN; ic++) {
        stage_ch(xb + ic * HW);
        const float* wz8 = wTz + ic * 72;
        const float* wr8 = wTr + ic * 72;
        const float* wh8 = wTh + (8 + ic) * 72;
#pragma unroll
        for (int ky = 0; ky < 3; ky++) {
#pragma unroll
            for (int kx = 0; kx < 3; kx++) {
                const int tn = (ky * 3 + kx) * 8;
                const int so = (ky * D) * SRx + kx * D;
                const float vc = stage[cbase + so];
                const float v0 = stage[hbase0 + so];
                const float v1 = stage[hbase1 + so];   // garbage if !hact1; ar1 then dead
#pragma unroll
                for (int o = 0; o < 8; o++) {
                    az[o] = fmaf(wz8[tn + o], vc, az[o]);
                    ah[o] = fmaf(wh8[tn + o], vc, ah[o]);
                    ar0[o] = fmaf(wr8[tn + o], v0, ar0[o]);
                    ar1[o] = fmaf(wr8[tn + o], v1, ar1[o]);
                }
            }
        }
    }
    // h channels (skipped at t==0: h==0 contributes nothing)
    if (has_h) {
        for (int ic = 0; ic < 8; ic++) {
            stage_ch(hprev + ic * HW);
            const float* wz8 = wTz + (XN + ic) * 72;
            const float* wr8 = wTr + (XN + ic) * 72;
#pragma unroll
            for (int ky = 0; ky < 3; ky++) {
#pragma unroll
                for (int kx = 0; kx < 3; kx++) {
                    const int tn = (ky * 3 + kx) * 8;
                    const int so = (ky * D) * SRx + kx * D;
                    const float vc = stage[cbase + so];
                    const float v0 = stage[hbase0 + so];
                    const float v1 = stage[hbase1 + so];
#pragma unroll
                    for (int o = 0; o < 8; o++) {
                        az[o] = fmaf(wz8[tn + o], vc, az[o]);
                        ar0[o] = fmaf(wr8[tn + o], v0, ar0[o]);
                        ar1[o] = fmaf(wr8[tn + o], v1, ar1[o]);
                    }
                }
            }
        }
    }

    // Build rh = sigmoid(ar+br)*hprev on the halo region in LDS.
    if (has_h) {
        const float* hb0 = hprev + hgoff0;
#pragma unroll
        for (int o = 0; o < 8; o++) {
            const float hv = hinb0 ? hb0[o * HW] : 0.0f;
            rhb[o * NE + tid] = sigm(ar0[o] + br[o]) * hv;
        }
        if (hact1) {
            const float* hb1 = hprev + hgoff1;
#pragma unroll
            for (int o = 0; o < 8; o++) {
                const float hv = hinb1 ? hb1[o * HW] : 0.0f;
                rhb[o * NE + 512 + tid] = sigm(ar1[o] + br[o]) * hv;
            }
        }
    } else {
#pragma unroll
        for (int o = 0; o < 8; o++) {
            rhb[o * NE + tid] = 0.0f;
            if (hact1) rhb[o * NE + 512 + tid] = 0.0f;
        }
    }
    __syncthreads();

    // h-conv rh-part (center only), taps entirely inside the halo region.
    const int hcb = ry * Ex + rx;
#pragma unroll
    for (int ic = 0; ic < 8; ic++) {
        const float* wh8 = wTh + ic * 72;
        const float* rb = rhb + ic * NE + hcb;
#pragma unroll
        for (int ky = 0; ky < 3; ky++) {
#pragma unroll
            for (int kx = 0; kx < 3; kx++) {
                const float v = rb[(ky * D) * Ex + kx * D];
                const int tn = (ky * 3 + kx) * 8;
#pragma unroll
                for (int o = 0; o < 8; o++) ah[o] = fmaf(wh8[tn + o], v, ah[o]);
            }
        }
    }

    // Gate epilogue: h_new = (1-z)*h + z*tanh(ah+bh)
#pragma unroll
    for (int o = 0; o < 8; o++) {
        const int idx = o * HW + gy * W_IMG + gx;
        const float z = sigm(az[o] + bz[o]);
        const float hc = tanh_fast(ah[o] + bh[o]);
        const float hv = has_h ? hprev[idx] : 0.0f;
        outp[idx] = (1.0f - z) * hv + z * hc;
    }
}

// ---------------------------------------------------------------------------
// Wave kernel: diagonal pipeline, one FUSED dispatch per wave. At wave w:
// unit0@t=w, unit1@t=w-1, unit2@t=w-2 (inter-unit deps are across dispatches
// only). Grid = 3 units x 8 batch x 32 tiles = 768 blocks of 512 = 3/CU.
// LDS = 1536 (stage) + 7680 (rh) floats = 36.9 KB.
// ---------------------------------------------------------------------------
struct WaveArgs {
    const float* X;
    float* hs;
    const float* wT;
    const float* bz[3];
    const float* br[3];
    const float* bh[3];
    int w;
};

__global__ __launch_bounds__(512, 6) void wave_kernel(WaveArgs a) {
    __shared__ float lds[9216];        // [0,1536): stage, [1536,9216): rh
    const int unit = blockIdx.x >> 8;
    const int t = a.w - unit;
    if ((unsigned)t >= (unsigned)T_STEPS) return;
    const int b = (blockIdx.x >> 5) & 7;
    const int tile = blockIdx.x & 31;          // 8 y-tiles x 4 x-tiles
    const int y0 = (tile >> 2) << 4, x0 = (tile & 3) << 5;
    float* hs = a.hs;
    const float* hprev = (t == 0) ? nullptr
                         : hs + (size_t)(((t - 1) * 4 + unit) * 8 + b) * (8 * HW);
    float* outp = hs + (size_t)((t * 4 + unit) * 8 + b) * (8 * HW);
    float* stage = lds;
    float* rhb = lds + 1536;

    if (unit == 0) {
        const float* xb = a.X + (size_t)(t * 8 + b) * HW;
        fused_unit<1, 1>(xb, hprev, outp, a.wT + 0, a.wT + 648, a.wT + 1296,
                         a.bz[0], a.br[0], a.bh[0], y0, x0, stage, rhb);
    } else if (unit == 1) {
        const float* xb = hs + (size_t)((t * 4 + 0) * 8 + b) * (8 * HW);
        fused_unit<2, 8>(xb, hprev, outp, a.wT + 1944, a.wT + 3096, a.wT + 4248,
                         a.bz[1], a.br[1], a.bh[1], y0, x0, stage, rhb);
    } else {
        const float* xb = hs + (size_t)((t * 4 + 1) * 8 + b) * (8 * HW);
        fused_unit<4, 8>(xb, hprev, outp, a.wT + 5400, a.wT + 6552, a.wT + 7704,
                         a.bz[2], a.br[2], a.bh[2], y0, x0, stage, rhb);
    }
}

// ---------------------------------------------------------------------------
// Head: y = sigmoid(conv1(relu(conv1(relu(conv2(h2)))))) fused per 32x16 tile,
// batched over all (t,b). LDS chain: h2[8][24][40] -> y1[8][20][36] ->
// y2[8][18][34] -> y[16][32].
// ---------------------------------------------------------------------------
struct HeadArgs {
    const float* hs;
    const float* wT;
    float* y;
    const float* bo1;
    const float* bo2;
    const float* bo;
};

__global__ __launch_bounds__(256) void head_kernel(HeadArgs a) {
    __shared__ float bufA[7680];   // h2 ext [8][24][40], later y2 [8][18][34]
    __shared__ float bufB[5760];   // y1 [8][20][36]
    const int tid = threadIdx.x;
    const int img = blockIdx.x >> 5;        // t*8 + b
    const int tile = blockIdx.x & 31;
    const int tx = tile & 3, tyy = tile >> 2;
    const int y0 = tyy * 16, x0 = tx * 32;
    const int t = img >> 3, b = img & 7;
    const float* h2 = a.hs + (size_t)((t * 4 + 2) * 8 + b) * (8 * HW);

    // P0: load h2 ext tile (zero-padded)
    for (int i = tid; i < 7680; i += 256) {
        const int c = i / 960, rem = i - c * 960;
        const int ey = rem / 40, ex = rem - ey * 40;
        const int gy = y0 - 4 + ey, gx = x0 - 4 + ex;
        float v = 0.0f;
        if (((unsigned)gy < 128u) && ((unsigned)gx < 128u)) v = h2[c * HW + gy * W_IMG + gx];
        bufA[i] = v;
    }
    __syncthreads();

    // P1: y1 = relu(conv d=2) on [8][20][36]
    {
        const float* wc = a.wT + 8856;
        float b1[8];
#pragma unroll
        for (int o = 0; o < 8; o++) b1[o] = a.bo1[o];
        for (int i = tid; i < 720; i += 256) {
            const int ey = i / 36, ex = i - ey * 36;
            const int gy = y0 - 2 + ey, gx = x0 - 2 + ex;
            const bool inb = ((unsigned)gy < 128u) & ((unsigned)gx < 128u);
            float acc[8];
#pragma unroll
            for (int o = 0; o < 8; o++) acc[o] = 0.0f;
            if (inb) {
                for (int ic = 0; ic < 8; ic++) {
#pragma unroll
                    for (int ky = 0; ky < 3; ky++) {
#pragma unroll
                        for (int kx = 0; kx < 3; kx++) {
                            const float v = bufA[(ic * 24 + ey + 2 + (ky - 1) * 2) * 40 + ex + 2 + (kx - 1) * 2];
                            const float* w8 = wc + ((ic * 3 + ky) * 3 + kx) * 8;
#pragma unroll
                            for (int o = 0; o < 8; o++) acc[o] = fmaf(w8[o], v, acc[o]);
                        }
                    }
                }
            }
#pragma unroll
            for (int o = 0; o < 8; o++)
                bufB[(o * 20 + ey) * 36 + ex] = inb ? fmaxf(acc[o] + b1[o], 0.0f) : 0.0f;
        }
    }
    __syncthreads();

    // P2: y2 = relu(conv d=1) on [8][18][34] -> bufA
    {
        const float* wc = a.wT + 9432;
        float b2[8];
#pragma unroll
        for (int o = 0; o < 8; o++) b2[o] = a.bo2[o];
        for (int i = tid; i < 612; i += 256) {
            const int ey = i / 34, ex = i - ey * 34;
            const int gy = y0 - 1 + ey, gx = x0 - 1 + ex;
            const bool inb = ((unsigned)gy < 128u) & ((unsigned)gx < 128u);
            float acc[8];
#pragma unroll
            for (int o = 0; o < 8; o++) acc[o] = 0.0f;
            if (inb) {
                for (int ic = 0; ic < 8; ic++) {
#pragma unroll
                    for (int ky = 0; ky < 3; ky++) {
#pragma unroll
                        for (int kx = 0; kx < 3; kx++) {
                            const float v = bufB[(ic * 20 + ey + 1 + (ky - 1)) * 36 + ex + 1 + (kx - 1)];
                            const float* w8 = wc + ((ic * 3 + ky) * 3 + kx) * 8;
#pragma unroll
                            for (int o = 0; o < 8; o++) acc[o] = fmaf(w8[o], v, acc[o]);
                        }
                    }
                }
            }
#pragma unroll
            for (int o = 0; o < 8; o++)
                bufA[(o * 18 + ey) * 34 + ex] = inb ? fmaxf(acc[o] + b2[o], 0.0f) : 0.0f;
        }
    }
    __syncthreads();

    // P3: y = sigmoid(conv d=1, 8->1) on [16][32]
    {
        const float* wc = a.wT + 10008;
        const float bo0 = a.bo[0];
        for (int i = tid; i < 512; i += 256) {
            const int ry = i >> 5, cx = i & 31;
            float acc = 0.0f;
            for (int ic = 0; ic < 8; ic++) {
#pragma unroll
                for (int ky = 0; ky < 3; ky++) {
#pragma unroll
                    for (int kx = 0; kx < 3; kx++) {
                        const float v = bufA[(ic * 18 + ry + 1 + (ky - 1)) * 34 + cx + 1 + (kx - 1)];
                        acc = fmaf(wc[((ic * 3 + ky) * 3 + kx) * 8], v, acc);
                    }
                }
            }
            a.y[(size_t)img * HW + (y0 + ry) * W_IMG + x0 + cx] = sigm(acc + bo0);
        }
    }
}

// ---------------------------------------------------------------------------
// Zero-fill hs[:,3] (including the wT scratch slice).
// ---------------------------------------------------------------------------
__global__ __launch_bounds__(256) void zero_kernel(float* hs) {
    const size_t i = (size_t)blockIdx.x * 256 + threadIdx.x;  // < 1310720
#pragma unroll
    for (int k = 0; k < 4; k++) {
        const size_t idx = i + (size_t)k * 1310720;  // float4 index < 5242880
        const size_t t = idx >> 18;                   // / 262144
        const size_t rem = idx & 262143;
        float4* p = (float4*)(hs + (t * 4 + 3) * (size_t)HS_SLICE);
        p[rem] = make_float4(0.0f, 0.0f, 0.0f, 0.0f);
    }
}

// ---------------------------------------------------------------------------
extern "C" void kernel_launch(void* const* d_in, const int* in_sizes, int n_in,
                              void* d_out, int out_size, void* d_ws, size_t ws_size,
                              hipStream_t stream) {
    (void)in_sizes; (void)n_in; (void)d_ws; (void)ws_size; (void)out_size;

    const float* X = (const float*)d_in[0];
    float* y  = (float*)d_out;
    float* hs = (float*)d_out + Y_SIZE;
    float* wT = hs + (size_t)79 * HS_SLICE;   // hs[19,3] slice as weight scratch

    PrepArgs pa;
    pa.w[0]  = (const float*)d_in[1];   // w1z
    pa.w[1]  = (const float*)d_in[3];   // w1r
    pa.w[2]  = (const float*)d_in[5];   // w1h
    pa.w[3]  = (const float*)d_in[7];   // w2z
    pa.w[4]  = (const float*)d_in[9];   // w2r
    pa.w[5]  = (const float*)d_in[11];  // w2h
    pa.w[6]  = (const float*)d_in[13];  // w3z
    pa.w[7]  = (const float*)d_in[15];  // w3r
    pa.w[8]  = (const float*)d_in[17];  // w3h
    pa.w[9]  = (const float*)d_in[19];  // wo1
    pa.w[10] = (const float*)d_in[21];  // wo2
    pa.w[11] = (const float*)d_in[23];  // wo
    pa.wT = wT;
    prep_kernel<<<dim3(12), dim3(256), 0, stream>>>(pa);

    WaveArgs wa;
    wa.X = X;
    wa.hs = hs;
    wa.wT = wT;
    wa.bz[0] = (const float*)d_in[2];  wa.br[0] = (const float*)d_in[4];  wa.bh[0] = (const float*)d_in[6];
    wa.bz[1] = (const float*)d_in[8];  wa.br[1] = (const float*)d_in[10]; wa.bh[1] = (const float*)d_in[12];
    wa.bz[2] = (const float*)d_in[14]; wa.br[2] = (const float*)d_in[16]; wa.bh[2] = (const float*)d_in[18];
    for (int w = 0; w < T_STEPS + 2; w++) {
        wa.w = w;
        wave_kernel<<<dim3(768), dim3(512), 0, stream>>>(wa);
    }

    HeadArgs ha;
    ha.hs = hs; ha.wT = wT; ha.y = y;
    ha.bo1 = (const float*)d_in[20];
    ha.bo2 = (const float*)d_in[22];
    ha.bo  = (const float*)d_in[24];
    head_kernel<<<dim3(5120), dim3(256), 0, stream>>>(ha);

    // zero hs[:,3] last (overwrites the wT scratch slice)
    zero_kernel<<<dim3(5120), dim3(256), 0, stream>>>(hs);
}

// Round 4
// 12868.924 us; speedup vs baseline: 1.8986x; 1.8986x over previous
//
#include <hip/hip_runtime.h>
#include <cstdint>
#include <cstddef>

// Problem constants
#define W_IMG 128
#define HW    16384            // 128*128
#define T_STEPS 20
#define BATCH 8
#define Y_SIZE 2621440         // 20*8*16384
#define HS_SLICE 1048576       // 8*8*16384  (one [t,s] slice)

__device__ __forceinline__ float sigm(float x) { return 1.0f / (1.0f + __expf(-x)); }
// tanh(x) = 1 - 2/(exp(2x)+1); safe at +/-inf, no NaN
__device__ __forceinline__ float tanh_fast(float x) { return 1.0f - 2.0f / (__expf(2.0f * x) + 1.0f); }

// ---------------------------------------------------------------------------
// Weight transpose: orig [oc][ic][3][3]  ->  wT [ic][ky][kx][oc(8)]
// wT lives in the hs[19,3] slice of d_out (written before use, zeroed last).
// ---------------------------------------------------------------------------
struct PrepArgs {
    const float* w[12];
    float* wT;
};

__global__ __launch_bounds__(256) void prep_kernel(PrepArgs a) {
    const int IC[12]  = {9, 9, 9, 16, 16, 16, 16, 16, 16, 8, 8, 8};
    const int OCc[12] = {8, 8, 8, 8, 8, 8, 8, 8, 8, 8, 8, 1};
    const int OFF[12] = {0, 648, 1296, 1944, 3096, 4248, 5400, 6552, 7704, 8856, 9432, 10008};
    const int c = blockIdx.x;           // one conv per block (grid = 12)
    const int n = IC[c] * 72;           // ic*9 taps * 8 oc (oc padded to 8)
    const float* ws = a.w[c];
    float* wd = a.wT + OFF[c];
    for (int i = threadIdx.x; i < n; i += 256) {
        const int o = i & 7;
        const int rest = i >> 3;                 // ic*9 + tap
        const int ic = rest / 9, tap = rest - ic * 9;
        float v = 0.0f;
        if (o < OCc[c]) v = ws[(o * IC[c] + ic) * 9 + tap];
        wd[i] = v;                               // dest index == (ic*9+tap)*8 + o == i
    }
}

// ---------------------------------------------------------------------------
// Fused GRU cell: one 16(y)x32(x) output tile, 512 threads (1 center px each).
// Per input channel (staged once in LDS, zero-padded):
//   - z-conv + h-conv-x-part accumulate at the center px
//   - r-conv accumulates on the extended halo (16+2D)x(32+2D) (KP=2 px/thr)
// Then rh = sigmoid(r + br) * hprev is built IN LDS on the halo region
// (hprev zero-padded => rh==0 outside image, matching the reference's
// zero-padded conv input), and the h-conv rh-part runs immediately.
// NOTE on launch bounds: round-3 used (512,6) which forced an ~85-VGPR cap
// and the allocator spilled the 32 accumulator regs to scratch -> 3.3 GB of
// spill traffic per dispatch (WRITE_SIZE 1.15 GB, VALUBusy 3%). (512,2)
// lifts the cap; ~110 VGPR expected -> 4 waves/EU, 2 blocks/CU, no spill.
// ---------------------------------------------------------------------------
template <int D, int XN>
__device__ void fused_unit(const float* __restrict__ xb, const float* __restrict__ hprev,
                           float* __restrict__ outp,
                           const float* __restrict__ wTz, const float* __restrict__ wTr,
                           const float* __restrict__ wTh,
                           const float* __restrict__ bz, const float* __restrict__ br,
                           const float* __restrict__ bh,
                           int y0, int x0, float* __restrict__ stage, float* __restrict__ rhb) {
    constexpr int Ey = 16 + 2 * D, Ex = 32 + 2 * D, NE = Ey * Ex;   // rh halo region
    constexpr int SRx = 32 + 4 * D, SRt = (16 + 4 * D) * SRx;       // staged region
    constexpr int NS = (SRt + 511) / 512;                           // stage slots/thread
    const int tid = threadIdx.x;
    const int ry = tid >> 5, rx = tid & 31;
    const int gy = y0 + ry, gx = x0 + rx;

    // Per-thread staging slots (hoisted out of the ic loop)
    int sgoff[NS]; bool sinb[NS], swr[NS];
#pragma unroll
    for (int s = 0; s < NS; s++) {
        const int i = s * 512 + tid;
        const int sy = i / SRx, sx = i - sy * SRx;
        const int yy = y0 - 2 * D + sy, xx = x0 - 2 * D + sx;
        swr[s] = (i < SRt);
        sinb[s] = swr[s] && ((unsigned)yy < 128u) && ((unsigned)xx < 128u);
        sgoff[s] = sinb[s] ? (yy * W_IMG + xx) : 0;
    }

    // Per-thread halo px assignment (2 slots; slot0 always active since NE>512)
    int hbase1, hgoff0, hgoff1; bool hact1, hinb0, hinb1;
    {
        const int ey = tid / Ex, ex = tid - ey * Ex;
        const int yy = y0 - D + ey, xx = x0 - D + ex;
        hinb0 = ((unsigned)yy < 128u) && ((unsigned)xx < 128u);
        hgoff0 = hinb0 ? (yy * W_IMG + xx) : 0;
    }
    const int hbase0 = (tid / Ex) * SRx + (tid - (tid / Ex) * Ex);
    {
        const int p = 512 + tid;
        const int ey = p / Ex, ex = p - ey * Ex;
        const int yy = y0 - D + ey, xx = x0 - D + ex;
        hact1 = (p < NE);
        hinb1 = hact1 && ((unsigned)yy < 128u) && ((unsigned)xx < 128u);
        hbase1 = ey * SRx + ex;
        hgoff1 = hinb1 ? (yy * W_IMG + xx) : 0;
    }
    const int cbase = (ry + D) * SRx + (rx + D);
    const bool has_h = (hprev != nullptr);

    float az[8], ah[8], ar0[8], ar1[8];
#pragma unroll
    for (int o = 0; o < 8; o++) { az[o] = 0.0f; ah[o] = 0.0f; ar0[o] = 0.0f; ar1[o] = 0.0f; }

    auto stage_ch = [&](const float* src) {
        __syncthreads();               // previous channel's LDS reads done
#pragma unroll
        for (int s = 0; s < NS; s++) {
            float v = 0.0f;
            if (sinb[s]) v = src[sgoff[s]];
            if (swr[s]) stage[s * 512 + tid] = v;
        }
        __syncthreads();
    };

    // x channels: z-conv (center) + h-conv x-part (center) + r-conv (halo)
    for (int ic = 0; ic < XN; ic++) {
        stage_ch(xb + ic * HW);
        const float* wz8 = wTz + ic * 72;
        const float* wr8 = wTr + ic * 72;
        const float* wh8 = wTh + (8 + ic) * 72;
#pragma unroll
        for (int ky = 0; ky < 3; ky++) {
#pragma unroll
            for (int kx = 0; kx < 3; kx++) {
                const int tn = (ky * 3 + kx) * 8;
                const int so = (ky * D) * SRx + kx * D;
                const float vc = stage[cbase + so];
                const float v0 = stage[hbase0 + so];
                const float v1 = stage[hbase1 + so];   // garbage if !hact1; ar1 then dead
#pragma unroll
                for (int o = 0; o < 8; o++) {
                    az[o] = fmaf(wz8[tn + o], vc, az[o]);
                    ah[o] = fmaf(wh8[tn + o], vc, ah[o]);
                    ar0[o] = fmaf(wr8[tn + o], v0, ar0[o]);
                    ar1[o] = fmaf(wr8[tn + o], v1, ar1[o]);
                }
            }
        }
    }
    // h channels (skipped at t==0: h==0 contributes nothing)
    if (has_h) {
        for (int ic = 0; ic < 8; ic++) {
            stage_ch(hprev + ic * HW);
            const float* wz8 = wTz + (XN + ic) * 72;
            const float* wr8 = wTr + (XN + ic) * 72;
#pragma unroll
            for (int ky = 0; ky < 3; ky++) {
#pragma unroll
                for (int kx = 0; kx < 3; kx++) {
                    const int tn = (ky * 3 + kx) * 8;
                    const int so = (ky * D) * SRx + kx * D;
                    const float vc = stage[cbase + so];
                    const float v0 = stage[hbase0 + so];
                    const float v1 = stage[hbase1 + so];
#pragma unroll
                    for (int o = 0; o < 8; o++) {
                        az[o] = fmaf(wz8[tn + o], vc, az[o]);
                        ar0[o] = fmaf(wr8[tn + o], v0, ar0[o]);
                        ar1[o] = fmaf(wr8[tn + o], v1, ar1[o]);
                    }
                }
            }
        }
    }

    // Build rh = sigmoid(ar+br)*hprev on the halo region in LDS.
    if (has_h) {
        const float* hb0 = hprev + hgoff0;
#pragma unroll
        for (int o = 0; o < 8; o++) {
            const float hv = hinb0 ? hb0[o * HW] : 0.0f;
            rhb[o * NE + tid] = sigm(ar0[o] + br[o]) * hv;
        }
        if (hact1) {
            const float* hb1 = hprev + hgoff1;
#pragma unroll
            for (int o = 0; o < 8; o++) {
                const float hv = hinb1 ? hb1[o * HW] : 0.0f;
                rhb[o * NE + 512 + tid] = sigm(ar1[o] + br[o]) * hv;
            }
        }
    } else {
#pragma unroll
        for (int o = 0; o < 8; o++) {
            rhb[o * NE + tid] = 0.0f;
            if (hact1) rhb[o * NE + 512 + tid] = 0.0f;
        }
    }
    __syncthreads();

    // h-conv rh-part (center only), taps entirely inside the halo region.
    const int hcb = ry * Ex + rx;
#pragma unroll
    for (int ic = 0; ic < 8; ic++) {
        const float* wh8 = wTh + ic * 72;
        const float* rb = rhb + ic * NE + hcb;
#pragma unroll
        for (int ky = 0; ky < 3; ky++) {
#pragma unroll
            for (int kx = 0; kx < 3; kx++) {
                const float v = rb[(ky * D) * Ex + kx * D];
                const int tn = (ky * 3 + kx) * 8;
#pragma unroll
                for (int o = 0; o < 8; o++) ah[o] = fmaf(wh8[tn + o], v, ah[o]);
            }
        }
    }

    // Gate epilogue: h_new = (1-z)*h + z*tanh(ah+bh)
#pragma unroll
    for (int o = 0; o < 8; o++) {
        const int idx = o * HW + gy * W_IMG + gx;
        const float z = sigm(az[o] + bz[o]);
        const float hc = tanh_fast(ah[o] + bh[o]);
        const float hv = has_h ? hprev[idx] : 0.0f;
        outp[idx] = (1.0f - z) * hv + z * hc;
    }
}

// ---------------------------------------------------------------------------
// Wave kernel: diagonal pipeline, one FUSED dispatch per wave. At wave w:
// unit0@t=w, unit1@t=w-1, unit2@t=w-2 (inter-unit deps are across dispatches
// only). Grid = 3 units x 8 batch x 32 tiles = 768 blocks of 512.
// LDS = 1536 (stage) + 7680 (rh) floats = 36.9 KB -> 2 blocks/CU at <=128 VGPR.
// ---------------------------------------------------------------------------
struct WaveArgs {
    const float* X;
    float* hs;
    const float* wT;
    const float* bz[3];
    const float* br[3];
    const float* bh[3];
    int w;
};

__global__ __launch_bounds__(512, 2) void wave_kernel(WaveArgs a) {
    __shared__ float lds[9216];        // [0,1536): stage, [1536,9216): rh
    const int unit = blockIdx.x >> 8;
    const int t = a.w - unit;
    if ((unsigned)t >= (unsigned)T_STEPS) return;
    const int b = (blockIdx.x >> 5) & 7;
    const int tile = blockIdx.x & 31;          // 8 y-tiles x 4 x-tiles
    const int y0 = (tile >> 2) << 4, x0 = (tile & 3) << 5;
    float* hs = a.hs;
    const float* hprev = (t == 0) ? nullptr
                         : hs + (size_t)(((t - 1) * 4 + unit) * 8 + b) * (8 * HW);
    float* outp = hs + (size_t)((t * 4 + unit) * 8 + b) * (8 * HW);
    float* stage = lds;
    float* rhb = lds + 1536;

    if (unit == 0) {
        const float* xb = a.X + (size_t)(t * 8 + b) * HW;
        fused_unit<1, 1>(xb, hprev, outp, a.wT + 0, a.wT + 648, a.wT + 1296,
                         a.bz[0], a.br[0], a.bh[0], y0, x0, stage, rhb);
    } else if (unit == 1) {
        const float* xb = hs + (size_t)((t * 4 + 0) * 8 + b) * (8 * HW);
        fused_unit<2, 8>(xb, hprev, outp, a.wT + 1944, a.wT + 3096, a.wT + 4248,
                         a.bz[1], a.br[1], a.bh[1], y0, x0, stage, rhb);
    } else {
        const float* xb = hs + (size_t)((t * 4 + 1) * 8 + b) * (8 * HW);
        fused_unit<4, 8>(xb, hprev, outp, a.wT + 5400, a.wT + 6552, a.wT + 7704,
                         a.bz[2], a.br[2], a.bh[2], y0, x0, stage, rhb);
    }
}

// ---------------------------------------------------------------------------
// Head: y = sigmoid(conv1(relu(conv1(relu(conv2(h2)))))) fused per 32x16 tile,
// batched over all (t,b). LDS chain: h2[8][24][40] -> y1[8][20][36] ->
// y2[8][18][34] -> y[16][32].
// ---------------------------------------------------------------------------
struct HeadArgs {
    const float* hs;
    const float* wT;
    float* y;
    const float* bo1;
    const float* bo2;
    const float* bo;
};

__global__ __launch_bounds__(256) void head_kernel(HeadArgs a) {
    __shared__ float bufA[7680];   // h2 ext [8][24][40], later y2 [8][18][34]
    __shared__ float bufB[5760];   // y1 [8][20][36]
    const int tid = threadIdx.x;
    const int img = blockIdx.x >> 5;        // t*8 + b
    const int tile = blockIdx.x & 31;
    const int tx = tile & 3, tyy = tile >> 2;
    const int y0 = tyy * 16, x0 = tx * 32;
    const int t = img >> 3, b = img & 7;
    const float* h2 = a.hs + (size_t)((t * 4 + 2) * 8 + b) * (8 * HW);

    // P0: load h2 ext tile (zero-padded)
    for (int i = tid; i < 7680; i += 256) {
        const int c = i / 960, rem = i - c * 960;
        const int ey = rem / 40, ex = rem - ey * 40;
        const int gy = y0 - 4 + ey, gx = x0 - 4 + ex;
        float v = 0.0f;
        if (((unsigned)gy < 128u) && ((unsigned)gx < 128u)) v = h2[c * HW + gy * W_IMG + gx];
        bufA[i] = v;
    }
    __syncthreads();

    // P1: y1 = relu(conv d=2) on [8][20][36]
    {
        const float* wc = a.wT + 8856;
        float b1[8];
#pragma unroll
        for (int o = 0; o < 8; o++) b1[o] = a.bo1[o];
        for (int i = tid; i < 720; i += 256) {
            const int ey = i / 36, ex = i - ey * 36;
            const int gy = y0 - 2 + ey, gx = x0 - 2 + ex;
            const bool inb = ((unsigned)gy < 128u) & ((unsigned)gx < 128u);
            float acc[8];
#pragma unroll
            for (int o = 0; o < 8; o++) acc[o] = 0.0f;
            if (inb) {
                for (int ic = 0; ic < 8; ic++) {
#pragma unroll
                    for (int ky = 0; ky < 3; ky++) {
#pragma unroll
                        for (int kx = 0; kx < 3; kx++) {
                            const float v = bufA[(ic * 24 + ey + 2 + (ky - 1) * 2) * 40 + ex + 2 + (kx - 1) * 2];
                            const float* w8 = wc + ((ic * 3 + ky) * 3 + kx) * 8;
#pragma unroll
                            for (int o = 0; o < 8; o++) acc[o] = fmaf(w8[o], v, acc[o]);
                        }
                    }
                }
            }
#pragma unroll
            for (int o = 0; o < 8; o++)
                bufB[(o * 20 + ey) * 36 + ex] = inb ? fmaxf(acc[o] + b1[o], 0.0f) : 0.0f;
        }
    }
    __syncthreads();

    // P2: y2 = relu(conv d=1) on [8][18][34] -> bufA
    {
        const float* wc = a.wT + 9432;
        float b2[8];
#pragma unroll
        for (int o = 0; o < 8; o++) b2[o] = a.bo2[o];
        for (int i = tid; i < 612; i += 256) {
            const int ey = i / 34, ex = i - ey * 34;
            const int gy = y0 - 1 + ey, gx = x0 - 1 + ex;
            const bool inb = ((unsigned)gy < 128u) & ((unsigned)gx < 128u);
            float acc[8];
#pragma unroll
            for (int o = 0; o < 8; o++) acc[o] = 0.0f;
            if (inb) {
                for (int ic = 0; ic < 8; ic++) {
#pragma unroll
                    for (int ky = 0; ky < 3; ky++) {
#pragma unroll
                        for (int kx = 0; kx < 3; kx++) {
                            const float v = bufB[(ic * 20 + ey + 1 + (ky - 1)) * 36 + ex + 1 + (kx - 1)];
                            const float* w8 = wc + ((ic * 3 + ky) * 3 + kx) * 8;
#pragma unroll
                            for (int o = 0; o < 8; o++) acc[o] = fmaf(w8[o], v, acc[o]);
                        }
                    }
                }
            }
#pragma unroll
            for (int o = 0; o < 8; o++)
                bufA[(o * 18 + ey) * 34 + ex] = inb ? fmaxf(acc[o] + b2[o], 0.0f) : 0.0f;
        }
    }
    __syncthreads();

    // P3: y = sigmoid(conv d=1, 8->1) on [16][32]
    {
        const float* wc = a.wT + 10008;
        const float bo0 = a.bo[0];
        for (int i = tid; i < 512; i += 256) {
            const int ry = i >> 5, cx = i & 31;
            float acc = 0.0f;
            for (int ic = 0; ic < 8; ic++) {
#pragma unroll
                for (int ky = 0; ky < 3; ky++) {
#pragma unroll
                    for (int kx = 0; kx < 3; kx++) {
                        const float v = bufA[(ic * 18 + ry + 1 + (ky - 1)) * 34 + cx + 1 + (kx - 1)];
                        acc = fmaf(wc[((ic * 3 + ky) * 3 + kx) * 8], v, acc);
                    }
                }
            }
            a.y[(size_t)img * HW + (y0 + ry) * W_IMG + x0 + cx] = sigm(acc + bo0);
        }
    }
}

// ---------------------------------------------------------------------------
// Zero-fill hs[:,3] (including the wT scratch slice).
// ---------------------------------------------------------------------------
__global__ __launch_bounds__(256) void zero_kernel(float* hs) {
    const size_t i = (size_t)blockIdx.x * 256 + threadIdx.x;  // < 1310720
#pragma unroll
    for (int k = 0; k < 4; k++) {
        const size_t idx = i + (size_t)k * 1310720;  // float4 index < 5242880
        const size_t t = idx >> 18;                   // / 262144
        const size_t rem = idx & 262143;
        float4* p = (float4*)(hs + (t * 4 + 3) * (size_t)HS_SLICE);
        p[rem] = make_float4(0.0f, 0.0f, 0.0f, 0.0f);
    }
}

// ---------------------------------------------------------------------------
extern "C" void kernel_launch(void* const* d_in, const int* in_sizes, int n_in,
                              void* d_out, int out_size, void* d_ws, size_t ws_size,
                              hipStream_t stream) {
    (void)in_sizes; (void)n_in; (void)d_ws; (void)ws_size; (void)out_size;

    const float* X = (const float*)d_in[0];
    float* y  = (float*)d_out;
    float* hs = (float*)d_out + Y_SIZE;
    float* wT = hs + (size_t)79 * HS_SLICE;   // hs[19,3] slice as weight scratch

    PrepArgs pa;
    pa.w[0]  = (const float*)d_in[1];   // w1z
    pa.w[1]  = (const float*)d_in[3];   // w1r
    pa.w[2]  = (const float*)d_in[5];   // w1h
    pa.w[3]  = (const float*)d_in[7];   // w2z
    pa.w[4]  = (const float*)d_in[9];   // w2r
    pa.w[5]  = (const float*)d_in[11];  // w2h
    pa.w[6]  = (const float*)d_in[13];  // w3z
    pa.w[7]  = (const float*)d_in[15];  // w3r
    pa.w[8]  = (const float*)d_in[17];  // w3h
    pa.w[9]  = (const float*)d_in[19];  // wo1
    pa.w[10] = (const float*)d_in[21];  // wo2
    pa.w[11] = (const float*)d_in[23];  // wo
    pa.wT = wT;
    prep_kernel<<<dim3(12), dim3(256), 0, stream>>>(pa);

    WaveArgs wa;
    wa.X = X;
    wa.hs = hs;
    wa.wT = wT;
    wa.bz[0] = (const float*)d_in[2];  wa.br[0] = (const float*)d_in[4];  wa.bh[0] = (const float*)d_in[6];
    wa.bz[1] = (const float*)d_in[8];  wa.br[1] = (const float*)d_in[10]; wa.bh[1] = (const float*)d_in[12];
    wa.bz[2] = (const float*)d_in[14]; wa.br[2] = (const float*)d_in[16]; wa.bh[2] = (const float*)d_in[18];
    for (int w = 0; w < T_STEPS + 2; w++) {
        wa.w = w;
        wave_kernel<<<dim3(768), dim3(512), 0, stream>>>(wa);
    }

    HeadArgs ha;
    ha.hs = hs; ha.wT = wT; ha.y = y;
    ha.bo1 = (const float*)d_in[20];
    ha.bo2 = (const float*)d_in[22];
    ha.bo  = (const float*)d_in[24];
    head_kernel<<<dim3(5120), dim3(256), 0, stream>>>(ha);

    // zero hs[:,3] last (overwrites the wT scratch slice)
    zero_kernel<<<dim3(5120), dim3(256), 0, stream>>>(hs);
}

// Round 5
// 2832.529 us; speedup vs baseline: 8.6260x; 4.5433x over previous
//
#include <hip/hip_runtime.h>
#include <cstdint>
#include <cstddef>

// Problem constants
#define W_IMG 128
#define HW    16384            // 128*128
#define T_STEPS 20
#define BATCH 8
#define Y_SIZE 2621440         // 20*8*16384
#define HS_SLICE 1048576       // 8*8*16384  (one [t,s] slice)

__device__ __forceinline__ float sigm(float x) { return 1.0f / (1.0f + __expf(-x)); }
// tanh(x) = 1 - 2/(exp(2x)+1); safe at +/-inf, no NaN
__device__ __forceinline__ float tanh_fast(float x) { return 1.0f - 2.0f / (__expf(2.0f * x) + 1.0f); }

// ---------------------------------------------------------------------------
// Weight transpose: orig [oc][ic][3][3]  ->  wT [ic][ky][kx][oc(8)]
// wT lives in the hs[19,3] slice of d_out (written before use, zeroed last).
// All wT offsets are multiples of 8 floats (32 B) -> float4 loads are legal.
// ---------------------------------------------------------------------------
struct PrepArgs {
    const float* w[12];
    float* wT;
};

__global__ __launch_bounds__(256) void prep_kernel(PrepArgs a) {
    const int IC[12]  = {9, 9, 9, 16, 16, 16, 16, 16, 16, 8, 8, 8};
    const int OCc[12] = {8, 8, 8, 8, 8, 8, 8, 8, 8, 8, 8, 1};
    const int OFF[12] = {0, 648, 1296, 1944, 3096, 4248, 5400, 6552, 7704, 8856, 9432, 10008};
    const int c = blockIdx.x;           // one conv per block (grid = 12)
    const int n = IC[c] * 72;           // ic*9 taps * 8 oc (oc padded to 8)
    const float* ws = a.w[c];
    float* wd = a.wT + OFF[c];
    for (int i = threadIdx.x; i < n; i += 256) {
        const int o = i & 7;
        const int rest = i >> 3;                 // ic*9 + tap
        const int ic = rest / 9, tap = rest - ic * 9;
        float v = 0.0f;
        if (o < OCc[c]) v = ws[(o * IC[c] + ic) * 9 + tap];
        wd[i] = v;                               // dest index == (ic*9+tap)*8 + o == i
    }
}

// ---------------------------------------------------------------------------
// Fused GRU cell: one 16(y)x32(x) output tile, 512 threads (1 center px each).
// Per input channel (staged once in LDS, zero-padded):
//   - z-conv + h-conv-x-part accumulate at the center px
//   - r-conv accumulates on the extended halo (16+2D)x(32+2D) (KP=2 px/thr)
// Then rh = sigmoid(r + br) * hprev is built IN LDS on the halo region, and
// the h-conv rh-part runs immediately. z never leaves registers.
//
// REGISTER-PRESSURE NOTE (rounds 3/4 post-mortem): with the ic/tap loops
// unrolled (compile-time trips), LLVM flattened ~1700 FMAs and hoisted
// weight/LDS loads across the whole region; live ranges ballooned and the
// 32 accumulators spilled to scratch (WRITE_SIZE 686 MB/dispatch, VALUBusy
// 5%). `#pragma unroll 1` on ic/ky/kx bounds the window to one tap:
// 24 FMAs + 6 float4 weight loads + 3 LDS reads ≈ 80 live VGPRs. Do NOT
// remove these pragmas.
// ---------------------------------------------------------------------------
template <int D, int XN>
__device__ void fused_unit(const float* __restrict__ xb, const float* __restrict__ hprev,
                           float* __restrict__ outp,
                           const float* __restrict__ wTz, const float* __restrict__ wTr,
                           const float* __restrict__ wTh,
                           const float* __restrict__ bz, const float* __restrict__ br,
                           const float* __restrict__ bh,
                           int y0, int x0, float* __restrict__ stage, float* __restrict__ rhb) {
    constexpr int Ey = 16 + 2 * D, Ex = 32 + 2 * D, NE = Ey * Ex;   // rh halo region
    constexpr int SRx = 32 + 4 * D, SRt = (16 + 4 * D) * SRx;       // staged region
    constexpr int NS = (SRt + 511) / 512;                           // stage slots/thread
    const int tid = threadIdx.x;
    const int ry = tid >> 5, rx = tid & 31;
    const int gy = y0 + ry, gx = x0 + rx;

    // Per-thread staging slots (hoisted out of the ic loop)
    int sgoff[NS]; bool sinb[NS], swr[NS];
#pragma unroll
    for (int s = 0; s < NS; s++) {
        const int i = s * 512 + tid;
        const int sy = i / SRx, sx = i - sy * SRx;
        const int yy = y0 - 2 * D + sy, xx = x0 - 2 * D + sx;
        swr[s] = (i < SRt);
        sinb[s] = swr[s] && ((unsigned)yy < 128u) && ((unsigned)xx < 128u);
        sgoff[s] = sinb[s] ? (yy * W_IMG + xx) : 0;
    }

    // Per-thread halo px assignment (2 slots; slot0 always active since NE>512)
    int hbase1, hgoff0, hgoff1; bool hact1, hinb0, hinb1;
    {
        const int ey = tid / Ex, ex = tid - ey * Ex;
        const int yy = y0 - D + ey, xx = x0 - D + ex;
        hinb0 = ((unsigned)yy < 128u) && ((unsigned)xx < 128u);
        hgoff0 = hinb0 ? (yy * W_IMG + xx) : 0;
    }
    const int hbase0 = (tid / Ex) * SRx + (tid - (tid / Ex) * Ex);
    {
        const int p = 512 + tid;
        const int ey = p / Ex, ex = p - ey * Ex;
        const int yy = y0 - D + ey, xx = x0 - D + ex;
        hact1 = (p < NE);
        hinb1 = hact1 && ((unsigned)yy < 128u) && ((unsigned)xx < 128u);
        hbase1 = ey * SRx + ex;
        hgoff1 = hinb1 ? (yy * W_IMG + xx) : 0;
    }
    const int cbase = (ry + D) * SRx + (rx + D);
    const bool has_h = (hprev != nullptr);

    float az[8], ah[8], ar0[8], ar1[8];
#pragma unroll
    for (int o = 0; o < 8; o++) { az[o] = 0.0f; ah[o] = 0.0f; ar0[o] = 0.0f; ar1[o] = 0.0f; }

    auto stage_ch = [&](const float* src) {
        __syncthreads();               // previous channel's LDS reads done
#pragma unroll
        for (int s = 0; s < NS; s++) {
            float v = 0.0f;
            if (sinb[s]) v = src[sgoff[s]];
            if (swr[s]) stage[s * 512 + tid] = v;
        }
        __syncthreads();
    };

    // x channels: z-conv (center) + h-conv x-part (center) + r-conv (halo)
#pragma unroll 1
    for (int ic = 0; ic < XN; ic++) {
        stage_ch(xb + ic * HW);
        const float* wz8 = wTz + ic * 72;
        const float* wr8 = wTr + ic * 72;
        const float* wh8 = wTh + (8 + ic) * 72;
#pragma unroll 1
        for (int ky = 0; ky < 3; ky++) {
#pragma unroll 1
            for (int kx = 0; kx < 3; kx++) {
                const int tn = (ky * 3 + kx) * 8;
                const int so = ky * (D * SRx) + kx * D;
                const float vc = stage[cbase + so];
                const float v0 = stage[hbase0 + so];
                const float v1 = stage[hbase1 + so];   // garbage if !hact1; ar1 then dead
                const float4 wza = *(const float4*)(wz8 + tn);
                const float4 wzb = *(const float4*)(wz8 + tn + 4);
                const float4 wra = *(const float4*)(wr8 + tn);
                const float4 wrb = *(const float4*)(wr8 + tn + 4);
                const float4 wha = *(const float4*)(wh8 + tn);
                const float4 whb = *(const float4*)(wh8 + tn + 4);
                az[0] = fmaf(wza.x, vc, az[0]); az[1] = fmaf(wza.y, vc, az[1]);
                az[2] = fmaf(wza.z, vc, az[2]); az[3] = fmaf(wza.w, vc, az[3]);
                az[4] = fmaf(wzb.x, vc, az[4]); az[5] = fmaf(wzb.y, vc, az[5]);
                az[6] = fmaf(wzb.z, vc, az[6]); az[7] = fmaf(wzb.w, vc, az[7]);
                ah[0] = fmaf(wha.x, vc, ah[0]); ah[1] = fmaf(wha.y, vc, ah[1]);
                ah[2] = fmaf(wha.z, vc, ah[2]); ah[3] = fmaf(wha.w, vc, ah[3]);
                ah[4] = fmaf(whb.x, vc, ah[4]); ah[5] = fmaf(whb.y, vc, ah[5]);
                ah[6] = fmaf(whb.z, vc, ah[6]); ah[7] = fmaf(whb.w, vc, ah[7]);
                ar0[0] = fmaf(wra.x, v0, ar0[0]); ar0[1] = fmaf(wra.y, v0, ar0[1]);
                ar0[2] = fmaf(wra.z, v0, ar0[2]); ar0[3] = fmaf(wra.w, v0, ar0[3]);
                ar0[4] = fmaf(wrb.x, v0, ar0[4]); ar0[5] = fmaf(wrb.y, v0, ar0[5]);
                ar0[6] = fmaf(wrb.z, v0, ar0[6]); ar0[7] = fmaf(wrb.w, v0, ar0[7]);
                ar1[0] = fmaf(wra.x, v1, ar1[0]); ar1[1] = fmaf(wra.y, v1, ar1[1]);
                ar1[2] = fmaf(wra.z, v1, ar1[2]); ar1[3] = fmaf(wra.w, v1, ar1[3]);
                ar1[4] = fmaf(wrb.x, v1, ar1[4]); ar1[5] = fmaf(wrb.y, v1, ar1[5]);
                ar1[6] = fmaf(wrb.z, v1, ar1[6]); ar1[7] = fmaf(wrb.w, v1, ar1[7]);
            }
        }
    }
    // h channels (skipped at t==0: h==0 contributes nothing)
    if (has_h) {
#pragma unroll 1
        for (int ic = 0; ic < 8; ic++) {
            stage_ch(hprev + ic * HW);
            const float* wz8 = wTz + (XN + ic) * 72;
            const float* wr8 = wTr + (XN + ic) * 72;
#pragma unroll 1
            for (int ky = 0; ky < 3; ky++) {
#pragma unroll 1
                for (int kx = 0; kx < 3; kx++) {
                    const int tn = (ky * 3 + kx) * 8;
                    const int so = ky * (D * SRx) + kx * D;
                    const float vc = stage[cbase + so];
                    const float v0 = stage[hbase0 + so];
                    const float v1 = stage[hbase1 + so];
                    const float4 wza = *(const float4*)(wz8 + tn);
                    const float4 wzb = *(const float4*)(wz8 + tn + 4);
                    const float4 wra = *(const float4*)(wr8 + tn);
                    const float4 wrb = *(const float4*)(wr8 + tn + 4);
                    az[0] = fmaf(wza.x, vc, az[0]); az[1] = fmaf(wza.y, vc, az[1]);
                    az[2] = fmaf(wza.z, vc, az[2]); az[3] = fmaf(wza.w, vc, az[3]);
                    az[4] = fmaf(wzb.x, vc, az[4]); az[5] = fmaf(wzb.y, vc, az[5]);
                    az[6] = fmaf(wzb.z, vc, az[6]); az[7] = fmaf(wzb.w, vc, az[7]);
                    ar0[0] = fmaf(wra.x, v0, ar0[0]); ar0[1] = fmaf(wra.y, v0, ar0[1]);
                    ar0[2] = fmaf(wra.z, v0, ar0[2]); ar0[3] = fmaf(wra.w, v0, ar0[3]);
                    ar0[4] = fmaf(wrb.x, v0, ar0[4]); ar0[5] = fmaf(wrb.y, v0, ar0[5]);
                    ar0[6] = fmaf(wrb.z, v0, ar0[6]); ar0[7] = fmaf(wrb.w, v0, ar0[7]);
                    ar1[0] = fmaf(wra.x, v1, ar1[0]); ar1[1] = fmaf(wra.y, v1, ar1[1]);
                    ar1[2] = fmaf(wra.z, v1, ar1[2]); ar1[3] = fmaf(wra.w, v1, ar1[3]);
                    ar1[4] = fmaf(wrb.x, v1, ar1[4]); ar1[5] = fmaf(wrb.y, v1, ar1[5]);
                    ar1[6] = fmaf(wrb.z, v1, ar1[6]); ar1[7] = fmaf(wrb.w, v1, ar1[7]);
                }
            }
        }
    }

    // Build rh = sigmoid(ar+br)*hprev on the halo region in LDS.
    if (has_h) {
        const float* hb0 = hprev + hgoff0;
#pragma unroll
        for (int o = 0; o < 8; o++) {
            const float hv = hinb0 ? hb0[o * HW] : 0.0f;
            rhb[o * NE + tid] = sigm(ar0[o] + br[o]) * hv;
        }
        if (hact1) {
            const float* hb1 = hprev + hgoff1;
#pragma unroll
            for (int o = 0; o < 8; o++) {
                const float hv = hinb1 ? hb1[o * HW] : 0.0f;
                rhb[o * NE + 512 + tid] = sigm(ar1[o] + br[o]) * hv;
            }
        }
    } else {
#pragma unroll
        for (int o = 0; o < 8; o++) {
            rhb[o * NE + tid] = 0.0f;
            if (hact1) rhb[o * NE + 512 + tid] = 0.0f;
        }
    }
    __syncthreads();

    // h-conv rh-part (center only), taps entirely inside the halo region.
    const int hcb = ry * Ex + rx;
#pragma unroll 1
    for (int ic = 0; ic < 8; ic++) {
        const float* wh8 = wTh + ic * 72;
        const float* rb = rhb + ic * NE + hcb;
#pragma unroll 1
        for (int ky = 0; ky < 3; ky++) {
#pragma unroll 1
            for (int kx = 0; kx < 3; kx++) {
                const float v = rb[ky * (D * Ex) + kx * D];
                const int tn = (ky * 3 + kx) * 8;
                const float4 wha = *(const float4*)(wh8 + tn);
                const float4 whb = *(const float4*)(wh8 + tn + 4);
                ah[0] = fmaf(wha.x, v, ah[0]); ah[1] = fmaf(wha.y, v, ah[1]);
                ah[2] = fmaf(wha.z, v, ah[2]); ah[3] = fmaf(wha.w, v, ah[3]);
                ah[4] = fmaf(whb.x, v, ah[4]); ah[5] = fmaf(whb.y, v, ah[5]);
                ah[6] = fmaf(whb.z, v, ah[6]); ah[7] = fmaf(whb.w, v, ah[7]);
            }
        }
    }

    // Gate epilogue: h_new = (1-z)*h + z*tanh(ah+bh)
#pragma unroll
    for (int o = 0; o < 8; o++) {
        const int idx = o * HW + gy * W_IMG + gx;
        const float z = sigm(az[o] + bz[o]);
        const float hc = tanh_fast(ah[o] + bh[o]);
        const float hv = has_h ? hprev[idx] : 0.0f;
        outp[idx] = (1.0f - z) * hv + z * hc;
    }
}

// ---------------------------------------------------------------------------
// Wave kernel: diagonal pipeline, one FUSED dispatch per wave. At wave w:
// unit0@t=w, unit1@t=w-1, unit2@t=w-2 (inter-unit deps are across dispatches
// only). Grid = 3 units x 8 batch x 32 tiles = 768 blocks of 512.
// LDS = 1536 (stage) + 7680 (rh) floats = 36.9 KB -> 2 blocks/CU at <=128 VGPR.
// ---------------------------------------------------------------------------
struct WaveArgs {
    const float* X;
    float* hs;
    const float* wT;
    const float* bz[3];
    const float* br[3];
    const float* bh[3];
    int w;
};

__global__ __launch_bounds__(512, 2) void wave_kernel(WaveArgs a) {
    __shared__ float lds[9216];        // [0,1536): stage, [1536,9216): rh
    const int unit = blockIdx.x >> 8;
    const int t = a.w - unit;
    if ((unsigned)t >= (unsigned)T_STEPS) return;
    const int b = (blockIdx.x >> 5) & 7;
    const int tile = blockIdx.x & 31;          // 8 y-tiles x 4 x-tiles
    const int y0 = (tile >> 2) << 4, x0 = (tile & 3) << 5;
    float* hs = a.hs;
    const float* hprev = (t == 0) ? nullptr
                         : hs + (size_t)(((t - 1) * 4 + unit) * 8 + b) * (8 * HW);
    float* outp = hs + (size_t)((t * 4 + unit) * 8 + b) * (8 * HW);
    float* stage = lds;
    float* rhb = lds + 1536;

    if (unit == 0) {
        const float* xb = a.X + (size_t)(t * 8 + b) * HW;
        fused_unit<1, 1>(xb, hprev, outp, a.wT + 0, a.wT + 648, a.wT + 1296,
                         a.bz[0], a.br[0], a.bh[0], y0, x0, stage, rhb);
    } else if (unit == 1) {
        const float* xb = hs + (size_t)((t * 4 + 0) * 8 + b) * (8 * HW);
        fused_unit<2, 8>(xb, hprev, outp, a.wT + 1944, a.wT + 3096, a.wT + 4248,
                         a.bz[1], a.br[1], a.bh[1], y0, x0, stage, rhb);
    } else {
        const float* xb = hs + (size_t)((t * 4 + 1) * 8 + b) * (8 * HW);
        fused_unit<4, 8>(xb, hprev, outp, a.wT + 5400, a.wT + 6552, a.wT + 7704,
                         a.bz[2], a.br[2], a.bh[2], y0, x0, stage, rhb);
    }
}

// ---------------------------------------------------------------------------
// Head: y = sigmoid(conv1(relu(conv1(relu(conv2(h2)))))) fused per 32x16 tile,
// batched over all (t,b). LDS chain: h2[8][24][40] -> y1[8][20][36] ->
// y2[8][18][34] -> y[16][32].
// ---------------------------------------------------------------------------
struct HeadArgs {
    const float* hs;
    const float* wT;
    float* y;
    const float* bo1;
    const float* bo2;
    const float* bo;
};

__global__ __launch_bounds__(256) void head_kernel(HeadArgs a) {
    __shared__ float bufA[7680];   // h2 ext [8][24][40], later y2 [8][18][34]
    __shared__ float bufB[5760];   // y1 [8][20][36]
    const int tid = threadIdx.x;
    const int img = blockIdx.x >> 5;        // t*8 + b
    const int tile = blockIdx.x & 31;
    const int tx = tile & 3, tyy = tile >> 2;
    const int y0 = tyy * 16, x0 = tx * 32;
    const int t = img >> 3, b = img & 7;
    const float* h2 = a.hs + (size_t)((t * 4 + 2) * 8 + b) * (8 * HW);

    // P0: load h2 ext tile (zero-padded)
    for (int i = tid; i < 7680; i += 256) {
        const int c = i / 960, rem = i - c * 960;
        const int ey = rem / 40, ex = rem - ey * 40;
        const int gy = y0 - 4 + ey, gx = x0 - 4 + ex;
        float v = 0.0f;
        if (((unsigned)gy < 128u) && ((unsigned)gx < 128u)) v = h2[c * HW + gy * W_IMG + gx];
        bufA[i] = v;
    }
    __syncthreads();

    // P1: y1 = relu(conv d=2) on [8][20][36]
    {
        const float* wc = a.wT + 8856;
        float b1[8];
#pragma unroll
        for (int o = 0; o < 8; o++) b1[o] = a.bo1[o];
        for (int i = tid; i < 720; i += 256) {
            const int ey = i / 36, ex = i - ey * 36;
            const int gy = y0 - 2 + ey, gx = x0 - 2 + ex;
            const bool inb = ((unsigned)gy < 128u) & ((unsigned)gx < 128u);
            float acc[8];
#pragma unroll
            for (int o = 0; o < 8; o++) acc[o] = 0.0f;
            if (inb) {
                for (int ic = 0; ic < 8; ic++) {
#pragma unroll
                    for (int ky = 0; ky < 3; ky++) {
#pragma unroll
                        for (int kx = 0; kx < 3; kx++) {
                            const float v = bufA[(ic * 24 + ey + 2 + (ky - 1) * 2) * 40 + ex + 2 + (kx - 1) * 2];
                            const float* w8 = wc + ((ic * 3 + ky) * 3 + kx) * 8;
#pragma unroll
                            for (int o = 0; o < 8; o++) acc[o] = fmaf(w8[o], v, acc[o]);
                        }
                    }
                }
            }
#pragma unroll
            for (int o = 0; o < 8; o++)
                bufB[(o * 20 + ey) * 36 + ex] = inb ? fmaxf(acc[o] + b1[o], 0.0f) : 0.0f;
        }
    }
    __syncthreads();

    // P2: y2 = relu(conv d=1) on [8][18][34] -> bufA
    {
        const float* wc = a.wT + 9432;
        float b2[8];
#pragma unroll
        for (int o = 0; o < 8; o++) b2[o] = a.bo2[o];
        for (int i = tid; i < 612; i += 256) {
            const int ey = i / 34, ex = i - ey * 34;
            const int gy = y0 - 1 + ey, gx = x0 - 1 + ex;
            const bool inb = ((unsigned)gy < 128u) & ((unsigned)gx < 128u);
            float acc[8];
#pragma unroll
            for (int o = 0; o < 8; o++) acc[o] = 0.0f;
            if (inb) {
                for (int ic = 0; ic < 8; ic++) {
#pragma unroll
                    for (int ky = 0; ky < 3; ky++) {
#pragma unroll
                        for (int kx = 0; kx < 3; kx++) {
                            const float v = bufB[(ic * 20 + ey + 1 + (ky - 1)) * 36 + ex + 1 + (kx - 1)];
                            const float* w8 = wc + ((ic * 3 + ky) * 3 + kx) * 8;
#pragma unroll
                            for (int o = 0; o < 8; o++) acc[o] = fmaf(w8[o], v, acc[o]);
                        }
                    }
                }
            }
#pragma unroll
            for (int o = 0; o < 8; o++)
                bufA[(o * 18 + ey) * 34 + ex] = inb ? fmaxf(acc[o] + b2[o], 0.0f) : 0.0f;
        }
    }
    __syncthreads();

    // P3: y = sigmoid(conv d=1, 8->1) on [16][32]
    {
        const float* wc = a.wT + 10008;
        const float bo0 = a.bo[0];
        for (int i = tid; i < 512; i += 256) {
            const int ry = i >> 5, cx = i & 31;
            float acc = 0.0f;
            for (int ic = 0; ic < 8; ic++) {
#pragma unroll
                for (int ky = 0; ky < 3; ky++) {
#pragma unroll
                    for (int kx = 0; kx < 3; kx++) {
                        const float v = bufA[(ic * 18 + ry + 1 + (ky - 1)) * 34 + cx + 1 + (kx - 1)];
                        acc = fmaf(wc[((ic * 3 + ky) * 3 + kx) * 8], v, acc);
                    }
                }
            }
            a.y[(size_t)img * HW + (y0 + ry) * W_IMG + x0 + cx] = sigm(acc + bo0);
        }
    }
}

// ---------------------------------------------------------------------------
// Zero-fill hs[:,3] (including the wT scratch slice).
// ---------------------------------------------------------------------------
__global__ __launch_bounds__(256) void zero_kernel(float* hs) {
    const size_t i = (size_t)blockIdx.x * 256 + threadIdx.x;  // < 1310720
#pragma unroll
    for (int k = 0; k < 4; k++) {
        const size_t idx = i + (size_t)k * 1310720;  // float4 index < 5242880
        const size_t t = idx >> 18;                   // / 262144
        const size_t rem = idx & 262143;
        float4* p = (float4*)(hs + (t * 4 + 3) * (size_t)HS_SLICE);
        p[rem] = make_float4(0.0f, 0.0f, 0.0f, 0.0f);
    }
}

// ---------------------------------------------------------------------------
extern "C" void kernel_launch(void* const* d_in, const int* in_sizes, int n_in,
                              void* d_out, int out_size, void* d_ws, size_t ws_size,
                              hipStream_t stream) {
    (void)in_sizes; (void)n_in; (void)d_ws; (void)ws_size; (void)out_size;

    const float* X = (const float*)d_in[0];
    float* y  = (float*)d_out;
    float* hs = (float*)d_out + Y_SIZE;
    float* wT = hs + (size_t)79 * HS_SLICE;   // hs[19,3] slice as weight scratch

    PrepArgs pa;
    pa.w[0]  = (const float*)d_in[1];   // w1z
    pa.w[1]  = (const float*)d_in[3];   // w1r
    pa.w[2]  = (const float*)d_in[5];   // w1h
    pa.w[3]  = (const float*)d_in[7];   // w2z
    pa.w[4]  = (const float*)d_in[9];   // w2r
    pa.w[5]  = (const float*)d_in[11];  // w2h
    pa.w[6]  = (const float*)d_in[13];  // w3z
    pa.w[7]  = (const float*)d_in[15];  // w3r
    pa.w[8]  = (const float*)d_in[17];  // w3h
    pa.w[9]  = (const float*)d_in[19];  // wo1
    pa.w[10] = (const float*)d_in[21];  // wo2
    pa.w[11] = (const float*)d_in[23];  // wo
    pa.wT = wT;
    prep_kernel<<<dim3(12), dim3(256), 0, stream>>>(pa);

    WaveArgs wa;
    wa.X = X;
    wa.hs = hs;
    wa.wT = wT;
    wa.bz[0] = (const float*)d_in[2];  wa.br[0] = (const float*)d_in[4];  wa.bh[0] = (const float*)d_in[6];
    wa.bz[1] = (const float*)d_in[8];  wa.br[1] = (const float*)d_in[10]; wa.bh[1] = (const float*)d_in[12];
    wa.bz[2] = (const float*)d_in[14]; wa.br[2] = (const float*)d_in[16]; wa.bh[2] = (const float*)d_in[18];
    for (int w = 0; w < T_STEPS + 2; w++) {
        wa.w = w;
        wave_kernel<<<dim3(768), dim3(512), 0, stream>>>(wa);
    }

    HeadArgs ha;
    ha.hs = hs; ha.wT = wT; ha.y = y;
    ha.bo1 = (const float*)d_in[20];
    ha.bo2 = (const float*)d_in[22];
    ha.bo  = (const float*)d_in[24];
    head_kernel<<<dim3(5120), dim3(256), 0, stream>>>(ha);

    // zero hs[:,3] last (overwrites the wT scratch slice)
    zero_kernel<<<dim3(5120), dim3(256), 0, stream>>>(hs);
}

// Round 7
// 1862.916 us; speedup vs baseline: 13.1157x; 1.5205x over previous
//
#include <hip/hip_runtime.h>
#include <cstdint>
#include <cstddef>

// Problem constants
#define W_IMG 128
#define HW    16384            // 128*128
#define T_STEPS 20
#define BATCH 8
#define Y_SIZE 2621440         // 20*8*16384
#define HS_SLICE 1048576       // 8*8*16384  (one [t,s] slice)

__device__ __forceinline__ float sigm(float x) { return 1.0f / (1.0f + __expf(-x)); }
// tanh(x) = 1 - 2/(exp(2x)+1); safe at +/-inf, no NaN
__device__ __forceinline__ float tanh_fast(float x) { return 1.0f - 2.0f / (__expf(2.0f * x) + 1.0f); }

// ---------------------------------------------------------------------------
// Weight transpose: orig [oc][ic][3][3]  ->  wT [ic][ky][kx][oc(8)]
// wT lives in the hs[19,3] slice of d_out (written before use, zeroed last).
// Per GRU unit the z/r/h blocks are CONTIGUOUS in wT (unit0 @0..1944,
// unit1 @1944..5400, unit2 @5400..8856) -> one linear LDS preload per block.
// ---------------------------------------------------------------------------
struct PrepArgs {
    const float* w[12];
    float* wT;
};

__global__ __launch_bounds__(256) void prep_kernel(PrepArgs a) {
    const int IC[12]  = {9, 9, 9, 16, 16, 16, 16, 16, 16, 8, 8, 8};
    const int OCc[12] = {8, 8, 8, 8, 8, 8, 8, 8, 8, 8, 8, 1};
    const int OFF[12] = {0, 648, 1296, 1944, 3096, 4248, 5400, 6552, 7704, 8856, 9432, 10008};
    const int c = blockIdx.x;           // one conv per block (grid = 12)
    const int n = IC[c] * 72;           // ic*9 taps * 8 oc (oc padded to 8)
    const float* ws = a.w[c];
    float* wd = a.wT + OFF[c];
    for (int i = threadIdx.x; i < n; i += 256) {
        const int o = i & 7;
        const int rest = i >> 3;                 // ic*9 + tap
        const int ic = rest / 9, tap = rest - ic * 9;
        float v = 0.0f;
        if (o < OCc[c]) v = ws[(o * IC[c] + ic) * 9 + tap];
        wd[i] = v;                               // dest index == (ic*9+tap)*8 + o == i
    }
}

// ---------------------------------------------------------------------------
// Fused GRU cell: one 16(y)x32(x) output tile, 512 threads (1 center px each).
//
// Round-5 post-mortem: the rolled tap loop re-loaded 24 weight floats from
// GLOBAL per tap (6x dwordx4) with vmcnt(0) waits before each 32-FMA body;
// no SWP in a rolled loop -> ~300 cyc exposed per tap -> ~20% VALU eff.
// This version:
//  - preloads the unit's 3 weight blocks into LDS once (<=13.8 KB); per-tap
//    weight reads are uniform-addr ds_read_b128 broadcasts.
//  - register-prefetches channel i+1's global loads during channel i's
//    compute (T14 issue-early/consume-late) -> staging latency off the
//    critical path; stage write consumes already-arrived registers.
//  - kx (trip 3) unrolled for a bounded ILP window; ky and ic stay
//    `#pragma unroll 1` (round-4 lesson: full unroll -> hoisting -> spill).
// ---------------------------------------------------------------------------
template <int D, int XN>
__device__ void fused_unit(const float* __restrict__ xb, const float* __restrict__ hprev,
                           float* __restrict__ outp,
                           const float* __restrict__ wTu,   // unit's weights in global
                           const float* __restrict__ bz, const float* __restrict__ br,
                           const float* __restrict__ bh,
                           int y0, int x0,
                           float* __restrict__ stage, float* __restrict__ rhb,
                           float* __restrict__ wlds) {
    constexpr int Ey = 16 + 2 * D, Ex = 32 + 2 * D, NE = Ey * Ex;   // rh halo region
    constexpr int SRx = 32 + 4 * D, SRt = (16 + 4 * D) * SRx;       // staged region
    constexpr int NS = (SRt + 511) / 512;                           // stage slots/thread
    constexpr int IC = XN + 8;
    constexpr int WN = 3 * IC * 72;                                 // z+r+h weight floats
    const int tid = threadIdx.x;
    const int ry = tid >> 5, rx = tid & 31;
    const int gy = y0 + ry, gx = x0 + rx;

    // Weight preload (visibility guaranteed by the first barrier below).
    for (int i = tid; i < WN; i += 512) wlds[i] = wTu[i];
    const float* wzL = wlds;
    const float* wrL = wlds + IC * 72;
    const float* whL = wlds + 2 * IC * 72;

    // Per-thread staging slots (hoisted out of the ic loop)
    int sgoff[NS]; bool sinb[NS], swr[NS];
#pragma unroll
    for (int s = 0; s < NS; s++) {
        const int i = s * 512 + tid;
        const int sy = i / SRx, sx = i - sy * SRx;
        const int yy = y0 - 2 * D + sy, xx = x0 - 2 * D + sx;
        swr[s] = (i < SRt);
        sinb[s] = swr[s] && ((unsigned)yy < 128u) && ((unsigned)xx < 128u);
        sgoff[s] = sinb[s] ? (yy * W_IMG + xx) : 0;
    }

    // Per-thread halo px assignment (2 slots; slot0 always active since NE>512)
    int hbase1, hgoff0, hgoff1; bool hact1, hinb0, hinb1;
    {
        const int ey = tid / Ex, ex = tid - ey * Ex;
        const int yy = y0 - D + ey, xx = x0 - D + ex;
        hinb0 = ((unsigned)yy < 128u) && ((unsigned)xx < 128u);
        hgoff0 = hinb0 ? (yy * W_IMG + xx) : 0;
    }
    const int hbase0 = (tid / Ex) * SRx + (tid - (tid / Ex) * Ex);
    {
        const int p = 512 + tid;
        const int ey = p / Ex, ex = p - ey * Ex;
        const int yy = y0 - D + ey, xx = x0 - D + ex;
        hact1 = (p < NE);
        hinb1 = hact1 && ((unsigned)yy < 128u) && ((unsigned)xx < 128u);
        hbase1 = ey * SRx + ex;
        hgoff1 = hinb1 ? (yy * W_IMG + xx) : 0;
    }
    const int cbase = (ry + D) * SRx + (rx + D);
    const bool has_h = (hprev != nullptr);
    const int ICe = has_h ? IC : XN;   // h==0 at t=0: skip h channels

    float az[8], ah[8], ar0[8], ar1[8];
#pragma unroll
    for (int o = 0; o < 8; o++) { az[o] = 0.0f; ah[o] = 0.0f; ar0[o] = 0.0f; ar1[o] = 0.0f; }

    // Prefetch channel 0 into registers (XN >= 1 so channel 0 is always x).
    float pv[NS];
#pragma unroll
    for (int s = 0; s < NS; s++) pv[s] = sinb[s] ? xb[sgoff[s]] : 0.0f;

#pragma unroll 1
    for (int i = 0; i < ICe; i++) {
        __syncthreads();               // prev channel's LDS reads done (i=0: weight preload)
#pragma unroll
        for (int s = 0; s < NS; s++) if (swr[s]) stage[s * 512 + tid] = pv[s];
        __syncthreads();
        // Issue next channel's loads NOW; they land during this channel's compute.
        if (i + 1 < ICe) {
            const float* nsrc = (i + 1 < XN) ? (xb + (i + 1) * HW) : (hprev + (i + 1 - XN) * HW);
#pragma unroll
            for (int s = 0; s < NS; s++) pv[s] = sinb[s] ? nsrc[sgoff[s]] : 0.0f;
        }
        const float* wz8 = wzL + i * 72;
        const float* wr8 = wrL + i * 72;
        if (i < XN) {
            // x channel: z-conv + h-conv x-part (center) + r-conv (halo)
            const float* wh8 = whL + (8 + i) * 72;
#pragma unroll 1
            for (int ky = 0; ky < 3; ky++) {
#pragma unroll
                for (int kx = 0; kx < 3; kx++) {
                    const int tn = (ky * 3 + kx) * 8;
                    const int so = ky * (D * SRx) + kx * D;
                    const float vc = stage[cbase + so];
                    const float v0 = stage[hbase0 + so];
                    const float v1 = stage[hbase1 + so];   // garbage if !hact1; ar1 then dead
                    const float4 wza = *(const float4*)(wz8 + tn);
                    const float4 wzb = *(const float4*)(wz8 + tn + 4);
                    const float4 wra = *(const float4*)(wr8 + tn);
                    const float4 wrb = *(const float4*)(wr8 + tn + 4);
                    const float4 wha = *(const float4*)(wh8 + tn);
                    const float4 whb = *(const float4*)(wh8 + tn + 4);
                    az[0] = fmaf(wza.x, vc, az[0]); az[1] = fmaf(wza.y, vc, az[1]);
                    az[2] = fmaf(wza.z, vc, az[2]); az[3] = fmaf(wza.w, vc, az[3]);
                    az[4] = fmaf(wzb.x, vc, az[4]); az[5] = fmaf(wzb.y, vc, az[5]);
                    az[6] = fmaf(wzb.z, vc, az[6]); az[7] = fmaf(wzb.w, vc, az[7]);
                    ah[0] = fmaf(wha.x, vc, ah[0]); ah[1] = fmaf(wha.y, vc, ah[1]);
                    ah[2] = fmaf(wha.z, vc, ah[2]); ah[3] = fmaf(wha.w, vc, ah[3]);
                    ah[4] = fmaf(whb.x, vc, ah[4]); ah[5] = fmaf(whb.y, vc, ah[5]);
                    ah[6] = fmaf(whb.z, vc, ah[6]); ah[7] = fmaf(whb.w, vc, ah[7]);
                    ar0[0] = fmaf(wra.x, v0, ar0[0]); ar0[1] = fmaf(wra.y, v0, ar0[1]);
                    ar0[2] = fmaf(wra.z, v0, ar0[2]); ar0[3] = fmaf(wra.w, v0, ar0[3]);
                    ar0[4] = fmaf(wrb.x, v0, ar0[4]); ar0[5] = fmaf(wrb.y, v0, ar0[5]);
                    ar0[6] = fmaf(wrb.z, v0, ar0[6]); ar0[7] = fmaf(wrb.w, v0, ar0[7]);
                    ar1[0] = fmaf(wra.x, v1, ar1[0]); ar1[1] = fmaf(wra.y, v1, ar1[1]);
                    ar1[2] = fmaf(wra.z, v1, ar1[2]); ar1[3] = fmaf(wra.w, v1, ar1[3]);
                    ar1[4] = fmaf(wrb.x, v1, ar1[4]); ar1[5] = fmaf(wrb.y, v1, ar1[5]);
                    ar1[6] = fmaf(wrb.z, v1, ar1[6]); ar1[7] = fmaf(wrb.w, v1, ar1[7]);
                }
            }
        } else {
            // h channel: z-conv (center) + r-conv (halo) only
#pragma unroll 1
            for (int ky = 0; ky < 3; ky++) {
#pragma unroll
                for (int kx = 0; kx < 3; kx++) {
                    const int tn = (ky * 3 + kx) * 8;
                    const int so = ky * (D * SRx) + kx * D;
                    const float vc = stage[cbase + so];
                    const float v0 = stage[hbase0 + so];
                    const float v1 = stage[hbase1 + so];
                    const float4 wza = *(const float4*)(wz8 + tn);
                    const float4 wzb = *(const float4*)(wz8 + tn + 4);
                    const float4 wra = *(const float4*)(wr8 + tn);
                    const float4 wrb = *(const float4*)(wr8 + tn + 4);
                    az[0] = fmaf(wza.x, vc, az[0]); az[1] = fmaf(wza.y, vc, az[1]);
                    az[2] = fmaf(wza.z, vc, az[2]); az[3] = fmaf(wza.w, vc, az[3]);
                    az[4] = fmaf(wzb.x, vc, az[4]); az[5] = fmaf(wzb.y, vc, az[5]);
                    az[6] = fmaf(wzb.z, vc, az[6]); az[7] = fmaf(wzb.w, vc, az[7]);
                    ar0[0] = fmaf(wra.x, v0, ar0[0]); ar0[1] = fmaf(wra.y, v0, ar0[1]);
                    ar0[2] = fmaf(wra.z, v0, ar0[2]); ar0[3] = fmaf(wra.w, v0, ar0[3]);
                    ar0[4] = fmaf(wrb.x, v0, ar0[4]); ar0[5] = fmaf(wrb.y, v0, ar0[5]);
                    ar0[6] = fmaf(wrb.z, v0, ar0[6]); ar0[7] = fmaf(wrb.w, v0, ar0[7]);
                    ar1[0] = fmaf(wra.x, v1, ar1[0]); ar1[1] = fmaf(wra.y, v1, ar1[1]);
                    ar1[2] = fmaf(wra.z, v1, ar1[2]); ar1[3] = fmaf(wra.w, v1, ar1[3]);
                    ar1[4] = fmaf(wrb.x, v1, ar1[4]); ar1[5] = fmaf(wrb.y, v1, ar1[5]);
                    ar1[6] = fmaf(wrb.z, v1, ar1[6]); ar1[7] = fmaf(wrb.w, v1, ar1[7]);
                }
            }
        }
    }

    // Build rh = sigmoid(ar+br)*hprev on the halo region in LDS.
    if (has_h) {
        const float* hb0 = hprev + hgoff0;
#pragma unroll
        for (int o = 0; o < 8; o++) {
            const float hv = hinb0 ? hb0[o * HW] : 0.0f;
            rhb[o * NE + tid] = sigm(ar0[o] + br[o]) * hv;
        }
        if (hact1) {
            const float* hb1 = hprev + hgoff1;
#pragma unroll
            for (int o = 0; o < 8; o++) {
                const float hv = hinb1 ? hb1[o * HW] : 0.0f;
                rhb[o * NE + 512 + tid] = sigm(ar1[o] + br[o]) * hv;
            }
        }
    } else {
#pragma unroll
        for (int o = 0; o < 8; o++) {
            rhb[o * NE + tid] = 0.0f;
            if (hact1) rhb[o * NE + 512 + tid] = 0.0f;
        }
    }
    __syncthreads();

    // h-conv rh-part (center only), taps entirely inside the halo region.
    const int hcb = ry * Ex + rx;
#pragma unroll 1
    for (int ic = 0; ic < 8; ic++) {
        const float* wh8 = whL + ic * 72;
        const float* rb = rhb + ic * NE + hcb;
#pragma unroll 1
        for (int ky = 0; ky < 3; ky++) {
#pragma unroll
            for (int kx = 0; kx < 3; kx++) {
                const float v = rb[ky * (D * Ex) + kx * D];
                const int tn = (ky * 3 + kx) * 8;
                const float4 wha = *(const float4*)(wh8 + tn);
                const float4 whb = *(const float4*)(wh8 + tn + 4);
                ah[0] = fmaf(wha.x, v, ah[0]); ah[1] = fmaf(wha.y, v, ah[1]);
                ah[2] = fmaf(wha.z, v, ah[2]); ah[3] = fmaf(wha.w, v, ah[3]);
                ah[4] = fmaf(whb.x, v, ah[4]); ah[5] = fmaf(whb.y, v, ah[5]);
                ah[6] = fmaf(whb.z, v, ah[6]); ah[7] = fmaf(whb.w, v, ah[7]);
            }
        }
    }

    // Gate epilogue: h_new = (1-z)*h + z*tanh(ah+bh)
#pragma unroll
    for (int o = 0; o < 8; o++) {
        const int idx = o * HW + gy * W_IMG + gx;
        const float z = sigm(az[o] + bz[o]);
        const float hc = tanh_fast(ah[o] + bh[o]);
        const float hv = has_h ? hprev[idx] : 0.0f;
        outp[idx] = (1.0f - z) * hv + z * hc;
    }
}

// ---------------------------------------------------------------------------
// Wave kernel: diagonal pipeline, one FUSED dispatch per wave. At wave w:
// unit0@t=w, unit1@t=w-1, unit2@t=w-2 (inter-unit deps are across dispatches
// only). Grid = 3 units x 8 batch x 32 tiles = 768 blocks of 512.
// LDS = 1536 (stage) + 7680 (rh) + 3456 (weights) floats = 50.7 KB.
// ---------------------------------------------------------------------------
struct WaveArgs {
    const float* X;
    float* hs;
    const float* wT;
    const float* bz[3];
    const float* br[3];
    const float* bh[3];
    int w;
};

__global__ __launch_bounds__(512, 2) void wave_kernel(WaveArgs a) {
    __shared__ float lds[12672];   // [0,1536) stage, [1536,9216) rh, [9216,12672) weights
    const int unit = blockIdx.x >> 8;
    const int t = a.w - unit;
    if ((unsigned)t >= (unsigned)T_STEPS) return;
    const int b = (blockIdx.x >> 5) & 7;
    const int tile = blockIdx.x & 31;          // 8 y-tiles x 4 x-tiles
    const int y0 = (tile >> 2) << 4, x0 = (tile & 3) << 5;
    float* hs = a.hs;
    const float* hprev = (t == 0) ? nullptr
                         : hs + (size_t)(((t - 1) * 4 + unit) * 8 + b) * (8 * HW);
    float* outp = hs + (size_t)((t * 4 + unit) * 8 + b) * (8 * HW);
    float* stage = lds;
    float* rhb = lds + 1536;
    float* wlds = lds + 9216;

    if (unit == 0) {
        const float* xb = a.X + (size_t)(t * 8 + b) * HW;
        fused_unit<1, 1>(xb, hprev, outp, a.wT + 0,
                         a.bz[0], a.br[0], a.bh[0], y0, x0, stage, rhb, wlds);
    } else if (unit == 1) {
        const float* xb = hs + (size_t)((t * 4 + 0) * 8 + b) * (8 * HW);
        fused_unit<2, 8>(xb, hprev, outp, a.wT + 1944,
                         a.bz[1], a.br[1], a.bh[1], y0, x0, stage, rhb, wlds);
    } else {
        const float* xb = hs + (size_t)((t * 4 + 1) * 8 + b) * (8 * HW);
        fused_unit<4, 8>(xb, hprev, outp, a.wT + 5400,
                         a.bz[2], a.br[2], a.bh[2], y0, x0, stage, rhb, wlds);
    }
}

// ---------------------------------------------------------------------------
// Head: y = sigmoid(conv1(relu(conv1(relu(conv2(h2)))))) fused per 32x16 tile,
// batched over all (t,b). LDS chain: h2[8][24][40] -> y1[8][20][36] ->
// y2[8][18][34] -> y[16][32].
// ---------------------------------------------------------------------------
struct HeadArgs {
    const float* hs;
    const float* wT;
    float* y;
    const float* bo1;
    const float* bo2;
    const float* bo;
};

__global__ __launch_bounds__(256) void head_kernel(HeadArgs a) {
    __shared__ float bufA[7680];   // h2 ext [8][24][40], later y2 [8][18][34]
    __shared__ float bufB[5760];   // y1 [8][20][36]
    const int tid = threadIdx.x;
    const int img = blockIdx.x >> 5;        // t*8 + b
    const int tile = blockIdx.x & 31;
    const int tx = tile & 3, tyy = tile >> 2;
    const int y0 = tyy * 16, x0 = tx * 32;
    const int t = img >> 3, b = img & 7;
    const float* h2 = a.hs + (size_t)((t * 4 + 2) * 8 + b) * (8 * HW);

    // P0: load h2 ext tile (zero-padded)
    for (int i = tid; i < 7680; i += 256) {
        const int c = i / 960, rem = i - c * 960;
        const int ey = rem / 40, ex = rem - ey * 40;
        const int gy = y0 - 4 + ey, gx = x0 - 4 + ex;
        float v = 0.0f;
        if (((unsigned)gy < 128u) && ((unsigned)gx < 128u)) v = h2[c * HW + gy * W_IMG + gx];
        bufA[i] = v;
    }
    __syncthreads();

    // P1: y1 = relu(conv d=2) on [8][20][36]
    {
        const float* wc = a.wT + 8856;
        float b1[8];
#pragma unroll
        for (int o = 0; o < 8; o++) b1[o] = a.bo1[o];
        for (int i = tid; i < 720; i += 256) {
            const int ey = i / 36, ex = i - ey * 36;
            const int gy = y0 - 2 + ey, gx = x0 - 2 + ex;
            const bool inb = ((unsigned)gy < 128u) & ((unsigned)gx < 128u);
            float acc[8];
#pragma unroll
            for (int o = 0; o < 8; o++) acc[o] = 0.0f;
            if (inb) {
                for (int ic = 0; ic < 8; ic++) {
#pragma unroll
                    for (int ky = 0; ky < 3; ky++) {
#pragma unroll
                        for (int kx = 0; kx < 3; kx++) {
                            const float v = bufA[(ic * 24 + ey + 2 + (ky - 1) * 2) * 40 + ex + 2 + (kx - 1) * 2];
                            const float* w8 = wc + ((ic * 3 + ky) * 3 + kx) * 8;
#pragma unroll
                            for (int o = 0; o < 8; o++) acc[o] = fmaf(w8[o], v, acc[o]);
                        }
                    }
                }
            }
#pragma unroll
            for (int o = 0; o < 8; o++)
                bufB[(o * 20 + ey) * 36 + ex] = inb ? fmaxf(acc[o] + b1[o], 0.0f) : 0.0f;
        }
    }
    __syncthreads();

    // P2: y2 = relu(conv d=1) on [8][18][34] -> bufA
    {
        const float* wc = a.wT + 9432;
        float b2[8];
#pragma unroll
        for (int o = 0; o < 8; o++) b2[o] = a.bo2[o];
        for (int i = tid; i < 612; i += 256) {
            const int ey = i / 34, ex = i - ey * 34;
            const int gy = y0 - 1 + ey, gx = x0 - 1 + ex;
            const bool inb = ((unsigned)gy < 128u) & ((unsigned)gx < 128u);
            float acc[8];
#pragma unroll
            for (int o = 0; o < 8; o++) acc[o] = 0.0f;
            if (inb) {
                for (int ic = 0; ic < 8; ic++) {
#pragma unroll
                    for (int ky = 0; ky < 3; ky++) {
#pragma unroll
                        for (int kx = 0; kx < 3; kx++) {
                            const float v = bufB[(ic * 20 + ey + 1 + (ky - 1)) * 36 + ex + 1 + (kx - 1)];
                            const float* w8 = wc + ((ic * 3 + ky) * 3 + kx) * 8;
#pragma unroll
                            for (int o = 0; o < 8; o++) acc[o] = fmaf(w8[o], v, acc[o]);
                        }
                    }
                }
            }
#pragma unroll
            for (int o = 0; o < 8; o++)
                bufA[(o * 18 + ey) * 34 + ex] = inb ? fmaxf(acc[o] + b2[o], 0.0f) : 0.0f;
        }
    }
    __syncthreads();

    // P3: y = sigmoid(conv d=1, 8->1) on [16][32]
    {
        const float* wc = a.wT + 10008;
        const float bo0 = a.bo[0];
        for (int i = tid; i < 512; i += 256) {
            const int ry = i >> 5, cx = i & 31;
            float acc = 0.0f;
            for (int ic = 0; ic < 8; ic++) {
#pragma unroll
                for (int ky = 0; ky < 3; ky++) {
#pragma unroll
                    for (int kx = 0; kx < 3; kx++) {
                        const float v = bufA[(ic * 18 + ry + 1 + (ky - 1)) * 34 + cx + 1 + (kx - 1)];
                        acc = fmaf(wc[((ic * 3 + ky) * 3 + kx) * 8], v, acc);
                    }
                }
            }
            a.y[(size_t)img * HW + (y0 + ry) * W_IMG + x0 + cx] = sigm(acc + bo0);
        }
    }
}

// ---------------------------------------------------------------------------
// Zero-fill hs[:,3] (including the wT scratch slice).
// ---------------------------------------------------------------------------
__global__ __launch_bounds__(256) void zero_kernel(float* hs) {
    const size_t i = (size_t)blockIdx.x * 256 + threadIdx.x;  // < 1310720
#pragma unroll
    for (int k = 0; k < 4; k++) {
        const size_t idx = i + (size_t)k * 1310720;  // float4 index < 5242880
        const size_t t = idx >> 18;                   // / 262144
        const size_t rem = idx & 262143;
        float4* p = (float4*)(hs + (t * 4 + 3) * (size_t)HS_SLICE);
        p[rem] = make_float4(0.0f, 0.0f, 0.0f, 0.0f);
    }
}

// ---------------------------------------------------------------------------
extern "C" void kernel_launch(void* const* d_in, const int* in_sizes, int n_in,
                              void* d_out, int out_size, void* d_ws, size_t ws_size,
                              hipStream_t stream) {
    (void)in_sizes; (void)n_in; (void)d_ws; (void)ws_size; (void)out_size;

    const float* X = (const float*)d_in[0];
    float* y  = (float*)d_out;
    float* hs = (float*)d_out + Y_SIZE;
    float* wT = hs + (size_t)79 * HS_SLICE;   // hs[19,3] slice as weight scratch

    PrepArgs pa;
    pa.w[0]  = (const float*)d_in[1];   // w1z
    pa.w[1]  = (const float*)d_in[3];   // w1r
    pa.w[2]  = (const float*)d_in[5];   // w1h
    pa.w[3]  = (const float*)d_in[7];   // w2z
    pa.w[4]  = (const float*)d_in[9];   // w2r
    pa.w[5]  = (const float*)d_in[11];  // w2h
    pa.w[6]  = (const float*)d_in[13];  // w3z
    pa.w[7]  = (const float*)d_in[15];  // w3r
    pa.w[8]  = (const float*)d_in[17];  // w3h
    pa.w[9]  = (const float*)d_in[19];  // wo1
    pa.w[10] = (const float*)d_in[21];  // wo2
    pa.w[11] = (const float*)d_in[23];  // wo
    pa.wT = wT;
    prep_kernel<<<dim3(12), dim3(256), 0, stream>>>(pa);

    WaveArgs wa;
    wa.X = X;
    wa.hs = hs;
    wa.wT = wT;
    wa.bz[0] = (const float*)d_in[2];  wa.br[0] = (const float*)d_in[4];  wa.bh[0] = (const float*)d_in[6];
    wa.bz[1] = (const float*)d_in[8];  wa.br[1] = (const float*)d_in[10]; wa.bh[1] = (const float*)d_in[12];
    wa.bz[2] = (const float*)d_in[14]; wa.br[2] = (const float*)d_in[16]; wa.bh[2] = (const float*)d_in[18];
    for (int w = 0; w < T_STEPS + 2; w++) {
        wa.w = w;
        wave_kernel<<<dim3(768), dim3(512), 0, stream>>>(wa);
    }

    HeadArgs ha;
    ha.hs = hs; ha.wT = wT; ha.y = y;
    ha.bo1 = (const float*)d_in[20];
    ha.bo2 = (const float*)d_in[22];
    ha.bo  = (const float*)d_in[24];
    head_kernel<<<dim3(5120), dim3(256), 0, stream>>>(ha);

    // zero hs[:,3] last (overwrites the wT scratch slice)
    zero_kernel<<<dim3(5120), dim3(256), 0, stream>>>(hs);
}